// Round 1
// baseline (668.972 us; speedup 1.0000x reference)
//
#include <hip/hip_runtime.h>
#include <hip/hip_bf16.h>
#include <math.h>

// Problem constants
#define NPTS  32768      // 8 * 4096 points
#define NPAIR 4096       // 64 * 64 (oc,ic) pairs
#define NC    23         // basis combos
#define PSPLIT 16        // pair-dimension grid split
#define PPB   (NPAIR / PSPLIT)   // 256 pairs per block
#define TPB   256

// ---------------- compile-time constant tables ----------------
namespace cgen {
constexpr double PI = 3.14159265358979323846264338327950288;
constexpr double fact(int n) { double r = 1; for (int i = 2; i <= n; ++i) r *= i; return r; }
constexpr double comb(int n, int k) { double r = 1; for (int i = 0; i < k; ++i) r = r * (n - i) / (i + 1); return r; }
constexpr double csqrt(double x) { double g = x > 1 ? x : 1.0; for (int i = 0; i < 100; ++i) g = 0.5 * (g + x / g); return g; }

struct Tables {
  int n[NC]; int l[NC]; int m[NC];
  double pref[NC];      // norm_r * Klm * (sqrt(2) if m != 0)
  double lag[NC][4];    // Laguerre poly coeffs (x^0..x^3)
};
constexpr Tables gen() {
  Tables t{};
  int idx = 0;
  for (int n = 1; n <= 4; ++n)
    for (int k = 0; k < 3; ++k)
      for (int m = -3; m <= 3; ++m) {
        int am = m < 0 ? -m : m;
        if (!(am <= k && k < n)) continue;
        t.n[idx] = n; t.l[idx] = k; t.m[idx] = m;
        double norm_r = csqrt((2.0 / n) * (2.0 / n) * (2.0 / n) * fact(n - k - 1) / (2.0 * n * fact(n + k)));
        double Klm = csqrt((2.0 * k + 1.0) / (4.0 * PI) * fact(k - am) / fact(k + am));
        t.pref[idx] = norm_r * Klm * (m != 0 ? csqrt(2.0) : 1.0);
        int kk = n - k - 1, a = 2 * k + 1;
        for (int i = 0; i < 4; ++i) t.lag[idx][i] = 0.0;
        for (int i = 0; i <= kk; ++i)
          t.lag[idx][i] = ((i & 1) ? -1.0 : 1.0) * comb(kk + a, kk - i) / fact(i);
        ++idx;
      }
  return t;
}
constexpr Tables T = gen();
} // namespace cgen

// ---------------- kernel ----------------
__global__ __launch_bounds__(TPB)
void dcconv_poly_einsum(const float* __restrict__ pos,
                        const float* __restrict__ coef,
                        float* __restrict__ out) {
  const int pt    = blockIdx.x * TPB + threadIdx.x;      // point index (b*4096 + p)
  const int pair0 = blockIdx.y * PPB;                    // first (oc,ic) pair for this block

  // ---- per-point geometry ----
  const float x = pos[3 * pt + 0];
  const float y = pos[3 * pt + 1];
  const float z = pos[3 * pt + 2];

  const float r   = sqrtf(x * x + y * y + z * z) + 1e-12f;
  const float ct  = z / r;
  const float st2 = fmaxf(1.0f - ct * ct, 0.0f);
  const float st  = sqrtf(st2);
  const float phi = atan2f(y, x);
  float sp, cp;
  sincosf(phi, &sp, &cp);
  const float c2p = cp * cp - sp * sp;     // cos(2*phi)
  const float s2p = 2.0f * sp * cp;        // sin(2*phi)

  float rho[5]; rho[0] = 0.0f; rho[1] = 2.0f * r; rho[2] = r; rho[3] = (2.0f / 3.0f) * r; rho[4] = 0.5f * r;
  float en[5];  en[0] = 0.0f;
  en[1] = expf(-r); en[2] = expf(-0.5f * r); en[3] = expf(-(1.0f / 3.0f) * r); en[4] = expf(-0.25f * r);

  // Associated Legendre P_l^{|m|}(ct) with Condon-Shortley phase
  float P[3][3] = {};
  P[0][0] = 1.0f;
  P[1][0] = ct;                    P[1][1] = -st;
  P[2][0] = 1.5f * ct * ct - 0.5f; P[2][1] = -3.0f * ct * st; P[2][2] = 3.0f * st2;

  float trig[5]; trig[0] = s2p; trig[1] = sp; trig[2] = 1.0f; trig[3] = cp; trig[4] = c2p;

  // ---- 23 basis values, all constants folded at compile time ----
  float poly[NC];
#pragma unroll
  for (int c = 0; c < NC; ++c) {
    const int n = cgen::T.n[c], l = cgen::T.l[c], m = cgen::T.m[c];
    const int am = m < 0 ? -m : m;
    const float rh = rho[n];
    const float L = (float)cgen::T.lag[c][0]
                  + rh * ((float)cgen::T.lag[c][1]
                  + rh * ((float)cgen::T.lag[c][2]
                  + rh *  (float)cgen::T.lag[c][3]));
    const float rl = (l == 0) ? 1.0f : ((l == 1) ? rh : rh * rh);
    poly[c] = (float)cgen::T.pref[c] * en[n] * rl * L * P[l][am] * trig[m + 2];
  }

  // ---- einsum slice: 256 pairs, dot-23 each, coalesced dword stores ----
  const float* __restrict__ cptr = coef + (size_t)pair0 * NC;   // wave-uniform address
  float* __restrict__ optr = out + (size_t)pair0 * NPTS + pt;
#pragma unroll 4
  for (int j = 0; j < PPB; ++j) {
    float acc = 0.0f;
#pragma unroll
    for (int c = 0; c < NC; ++c) acc = fmaf(cptr[c], poly[c], acc);
    *optr = acc;
    cptr += NC;
    optr += NPTS;
  }
}

// ---------------- launch ----------------
extern "C" void kernel_launch(void* const* d_in, const int* in_sizes, int n_in,
                              void* d_out, int out_size, void* d_ws, size_t ws_size,
                              hipStream_t stream) {
  const float* pos  = (const float*)d_in[0];   // (8, 4096, 3) fp32
  const float* coef = (const float*)d_in[1];   // (64, 64, 23) fp32
  float* out = (float*)d_out;                  // (64, 64, 8, 4096) fp32

  dim3 grid(NPTS / TPB, PSPLIT);
  dim3 block(TPB);
  hipLaunchKernelGGL(dcconv_poly_einsum, grid, block, 0, stream, pos, coef, out);
}